// Round 15
// baseline (499.482 us; speedup 1.0000x reference)
//
#include <hip/hip_runtime.h>
#include <math.h>

#define N_NODES 100000
#define S1 50
#define S2 10
#define HID 128
#define NT 64          // nodes per block in enc2_mlp (lane = node)
#define AST 66         // act row stride in doubles ([k][n] rows, 16B-aligned)

// transposed fp64 weight sizes
#define W2_ELEMS   (128 * 128)     // Wt2[k][o]
#define WA_ELEMS   (129 * 128)     // Wta[k][o], k=128 row = remaining-space col
#define WB_ELEMS   (128 * 64)      // Wtb[k][o]
#define PAD_ELEMS  (W2_ELEMS + WA_ELEMS + WB_ELEMS)   // 41088

// ---------------- kernel 1: agg1 (fp64) fused with weight transpose+fp64-convert
__global__ __launch_bounds__(256) void prep_kernel(
    const float* __restrict__ feat, const int* __restrict__ neigh1,
    const float* __restrict__ W2, const float* __restrict__ w_a,
    const float* __restrict__ w_b,
    double* __restrict__ agg1d, double* __restrict__ wt)
{
    if (blockIdx.x >= 25000) {   // tail blocks: build transposed fp64 weights
        int i = (blockIdx.x - 25000) * 256 + threadIdx.x;
        if (i < W2_ELEMS) {
            int k = i >> 7, o = i & 127;
            wt[i] = (double)W2[o * 128 + k];
        } else if (i < W2_ELEMS + WA_ELEMS) {
            int j = i - W2_ELEMS;
            int k = j >> 7, o = j & 127;
            wt[i] = (double)w_a[o * 129 + k];
        } else if (i < PAD_ELEMS) {
            int j = i - W2_ELEMS - WA_ELEMS;
            int k = j >> 6, o = j & 63;
            wt[i] = (double)w_b[o * 128 + k];
        }
        return;
    }
    const int wid  = threadIdx.x >> 6;
    const int lane = threadIdx.x & 63;
    const int n = blockIdx.x * 4 + wid;
    if (n >= N_NODES) return;

    double f0 = 0.0, f1 = 0.0, f2 = 0.0;
    if (lane < S1) {
        int j = neigh1[n * S1 + lane];
        f0 = (double)feat[j * 3 + 0];
        f1 = (double)feat[j * 3 + 1];
        f2 = (double)feat[j * 3 + 2];
    } else if (lane == S1) {
        f0 = (double)feat[n * 3 + 0];
        f1 = (double)feat[n * 3 + 1];
        f2 = (double)feat[n * 3 + 2];
    }
    #pragma unroll
    for (int off = 32; off > 0; off >>= 1) {
        f0 += __shfl_down(f0, off);
        f1 += __shfl_down(f1, off);
        f2 += __shfl_down(f2, off);
    }
    if (lane == 0) {
        agg1d[n * 3 + 0] = f0 / 51.0;
        agg1d[n * 3 + 1] = f1 / 51.0;
        agg1d[n * 3 + 2] = f2 / 51.0;
    }
}

// ---------------- kernel 2: enc2 + MLP + score, fp64, SCALAR-PIPE weights.
// 512 threads (8 waves), 64 nodes/block (lane = node), 1563 blocks.
// Wave w owns outs [16w,16w+16). Weight addresses depend only on
// (wave,k,j) — forced wave-uniform via readfirstlane -> compiler emits
// s_load (scalar cache), freeing the VMEM/L1 vector path entirely.
// Per wave per k: 1 ds_read_b64 (act, lane-consecutive, conflict-free)
// + 128 B scalar weight fetch + 16 fp64 FMAs. LDS 67.6 KB -> 2 blocks/CU
// = 16 waves/CU. Acts in-place in sX[k][n] (read-all / barrier / write).
__global__ __launch_bounds__(512, 4) void enc2_mlp_kernel(
    const int* __restrict__ nodes, const int* __restrict__ neigh2,
    const double* __restrict__ agg1d,
    const float* __restrict__ W1, const double* __restrict__ wt,
    const float* __restrict__ b_a, const float* __restrict__ b_b,
    const float* __restrict__ w_c, const float* __restrict__ b_c,
    const int* __restrict__ psz, const int* __restrict__ npe,
    double* __restrict__ scoresd)
{
    __shared__ __align__(16) double sX[HID * AST];      // 67584 B, acts [k][n]

    const int tid  = threadIdx.x;
    const int n    = tid & 63;                           // lane = node col
    const int w    = __builtin_amdgcn_readfirstlane(tid >> 6);  // wave id 0..7 (SGPR)
    const int base = blockIdx.x * NT;

    // ---- phase 0+1: per-lane gather (33 doubles in regs) then
    // agg2[t][n] = mean_j relu(W1[t].row_j) for wave's t-range
    {
        int nidx = base + n; if (nidx >= N_NODES) nidx = N_NODES - 1;  // clamp tail
        int node = nodes[nidx];
        double g0[11], g1[11], g2[11];
        #pragma unroll
        for (int j = 0; j <= S2; j++) {
            int src = (j == 0) ? node : neigh2[node * S2 + (j - 1)];
            g0[j] = agg1d[src * 3 + 0];
            g1[j] = agg1d[src * 3 + 1];
            g2[j] = agg1d[src * 3 + 2];
        }
        #pragma unroll
        for (int s = 0; s < 16; s++) {
            int t = 16 * w + s;                          // uniform -> W1 via s_load
            double wx = (double)W1[t * 3 + 0];
            double wy = (double)W1[t * 3 + 1];
            double wz = (double)W1[t * 3 + 2];
            double acc = 0.0;
            #pragma unroll
            for (int j = 0; j <= S2; j++)
                acc += fmax(wx * g0[j] + wy * g1[j] + wz * g2[j], 0.0);
            sX[t * AST + n] = acc / 11.0;                // lane-consecutive write
        }
    }
    __syncthreads();

    // ---- phase 2: emb = relu(W2 @ agg2), in-place
    {
        double acc[16] = {};
        const double* __restrict__ wk = wt + 16 * w;     // uniform base (Wt2)
        #pragma unroll 4
        for (int k = 0; k < 128; k++) {
            double a = sX[k * AST + n];
            #pragma unroll
            for (int j = 0; j < 16; j++)
                acc[j] += wk[k * 128 + j] * a;           // scalar loads
        }
        __syncthreads();                                 // all reads done
        #pragma unroll
        for (int j = 0; j < 16; j++)
            sX[(16 * w + j) * AST + n] = fmax(acc[j], 0.0);
    }
    __syncthreads();

    // ---- phase 3: xa = relu(w_a[:,:128] @ emb + w_a[:,128]*rem + b_a), in-place
    {
        double acc[16] = {};
        const double* __restrict__ wk = wt + W2_ELEMS + 16 * w;   // Wta
        #pragma unroll 4
        for (int k = 0; k < 128; k++) {
            double a = sX[k * AST + n];
            #pragma unroll
            for (int j = 0; j < 16; j++)
                acc[j] += wk[k * 128 + j] * a;
        }
        const double rem = (double)(psz[0] - npe[0]);
        __syncthreads();                                 // all reads done
        #pragma unroll
        for (int j = 0; j < 16; j++) {
            int o = 16 * w + j;
            double ad = wt[W2_ELEMS + 128 * 128 + o] * rem + (double)b_a[o];
            sX[o * AST + n] = fmax(acc[j] + ad, 0.0);
        }
    }
    __syncthreads();

    // ---- phase 4: xb = relu(w_b @ xa + b_b), in-place rows 0..63
    {
        double acc[8] = {};
        const double* __restrict__ wk = wt + W2_ELEMS + WA_ELEMS + 8 * w;  // Wtb
        #pragma unroll 4
        for (int k = 0; k < 128; k++) {
            double a = sX[k * AST + n];
            #pragma unroll
            for (int j = 0; j < 8; j++)
                acc[j] += wk[k * 64 + j] * a;
        }
        __syncthreads();                                 // all reads done
        #pragma unroll
        for (int j = 0; j < 8; j++) {
            int o = 8 * w + j;
            sX[o * AST + n] = fmax(acc[j] + (double)b_b[o], 0.0);
        }
    }
    __syncthreads();

    // ---- phase 5: score = w_c . xb + b_c   (wave 0; lane n = node)
    if (w == 0) {
        double v = 0.0;
        #pragma unroll 8
        for (int o = 0; o < 64; o++)
            v += (double)w_c[o] * sX[o * AST + n];       // lane-consecutive reads
        if (base + n < N_NODES)
            scoresd[base + n] = v + (double)b_c[0];
    }
}

// ---------------- softmax chain: 3 kernels ----------------
__global__ __launch_bounds__(256) void reduce_max_kernel(
    const double* __restrict__ s, double* __restrict__ pmax)
{
    __shared__ double red[4];
    const int tid = threadIdx.x;
    double m = -INFINITY;
    for (int i = blockIdx.x * 256 + tid; i < N_NODES; i += gridDim.x * 256)
        m = fmax(m, s[i]);
    #pragma unroll
    for (int off = 32; off > 0; off >>= 1) m = fmax(m, __shfl_down(m, off));
    if ((tid & 63) == 0) red[tid >> 6] = m;
    __syncthreads();
    if (tid == 0)
        pmax[blockIdx.x] = fmax(fmax(red[0], red[1]), fmax(red[2], red[3]));
}

__global__ __launch_bounds__(256) void exp_sum_kernel(
    double* __restrict__ s, const double* __restrict__ pmax,
    double* __restrict__ psum)
{
    __shared__ double red[4];
    const int tid = threadIdx.x;
    double m = pmax[tid];
    #pragma unroll
    for (int off = 32; off > 0; off >>= 1) m = fmax(m, __shfl_down(m, off));
    if ((tid & 63) == 0) red[tid >> 6] = m;
    __syncthreads();
    m = fmax(fmax(red[0], red[1]), fmax(red[2], red[3]));
    __syncthreads();

    double acc = 0.0;
    for (int i = blockIdx.x * 256 + tid; i < N_NODES; i += gridDim.x * 256) {
        double e = exp(s[i] - m);
        s[i] = e;
        acc += e;
    }
    #pragma unroll
    for (int off = 32; off > 0; off >>= 1) acc += __shfl_down(acc, off);
    if ((tid & 63) == 0) red[tid >> 6] = acc;
    __syncthreads();
    if (tid == 0)
        psum[blockIdx.x] = (red[0] + red[1]) + (red[2] + red[3]);
}

__global__ __launch_bounds__(256) void scale_kernel(
    const double* __restrict__ e, const double* __restrict__ psum,
    float* __restrict__ out)
{
    __shared__ double red[4];
    const int tid = threadIdx.x;
    double acc = psum[tid];
    #pragma unroll
    for (int off = 32; off > 0; off >>= 1) acc += __shfl_down(acc, off);
    if ((tid & 63) == 0) red[tid >> 6] = acc;
    __syncthreads();
    const double invS = 1.0 / ((red[0] + red[1]) + (red[2] + red[3]));
    const int i = blockIdx.x * 256 + tid;
    if (i < N_NODES) out[i] = (float)(e[i] * invS);
}

// ---------------- launch ----------------
extern "C" void kernel_launch(void* const* d_in, const int* in_sizes, int n_in,
                              void* d_out, int out_size, void* d_ws, size_t ws_size,
                              hipStream_t stream)
{
    const int*   nodes = (const int*)  d_in[0];
    const float* feat  = (const float*)d_in[1];
    const int*   n1    = (const int*)  d_in[2];
    const int*   n2    = (const int*)  d_in[3];
    const float* W1    = (const float*)d_in[4];
    const float* W2    = (const float*)d_in[5];
    const float* w_a   = (const float*)d_in[6];
    const float* b_a   = (const float*)d_in[7];
    const float* w_b   = (const float*)d_in[8];
    const float* b_b   = (const float*)d_in[9];
    const float* w_c   = (const float*)d_in[10];
    const float* b_c   = (const float*)d_in[11];
    const int*   psz   = (const int*)  d_in[12];
    const int*   npe   = (const int*)  d_in[13];
    float* out = (float*)d_out;

    double* agg1d   = (double*)d_ws;                       // 300000
    double* scoresd = agg1d + (size_t)N_NODES * 3;         // 100000
    double* pmax    = scoresd + N_NODES;                   // 256
    double* psum    = pmax + 256;                          // 256
    double* wt      = psum + 256;                          // PAD_ELEMS fp64

    const int pad_blocks = (PAD_ELEMS + 255) / 256;        // 161
    prep_kernel<<<25000 + pad_blocks, 256, 0, stream>>>(
        feat, n1, W2, w_a, w_b, agg1d, wt);
    enc2_mlp_kernel<<<(N_NODES + NT - 1) / NT, 512, 0, stream>>>(
        nodes, n2, agg1d, W1, wt, b_a, b_b, w_c, b_c, psz, npe, scoresd);
    reduce_max_kernel<<<256, 256, 0, stream>>>(scoresd, pmax);
    exp_sum_kernel<<<256, 256, 0, stream>>>(scoresd, pmax, psum);
    scale_kernel<<<(N_NODES + 255) / 256, 256, 0, stream>>>(scoresd, psum, out);
}